// Round 6
// baseline (328.052 us; speedup 1.0000x reference)
//
#include <hip/hip_runtime.h>
#include <hip/hip_bf16.h>

// Problem constants (B,S,D) = (8, 2048, 1024), fp32 in/out, causal mask = tril.
#define Bb 8
#define Ss 2048
#define Dd 1024

typedef short bf16x8 __attribute__((ext_vector_type(8)));
typedef float f32x4  __attribute__((ext_vector_type(4)));

__device__ __forceinline__ short f2bf(float f) {
  union { __hip_bfloat16 h; short s; } u;
  u.h = __float2bfloat16(f);
  return u.s;
}
__device__ __forceinline__ float bf2f(short s) {
  union { unsigned int u; float f; } v;
  v.u = ((unsigned int)(unsigned short)s) << 16;
  return v.f;
}

// bf16 LDS tile [128][64]: 8 16B-slots/row, slot XOR-swizzled by row&7.
__device__ __forceinline__ int swz(int row, int slot) {
  return row * 64 + (((slot ^ row) & 7) << 3);
}
// Packed layout for a 256x32 bf16 matrix in a [128][64] tile:
// matrix (r,k) -> LDS row R=r>>1, slot=((r&1)<<2)|(k>>3), elem k&7, slot^=R&7.
__device__ __forceinline__ int swzp(int r, int lk) {
  int R = r >> 1;
  int slot = ((r & 1) << 2) | lk;
  return R * 64 + (((slot ^ R) & 7) << 3);
}

__device__ __forceinline__ void gld16(const short* g, short* l) {
  __builtin_amdgcn_global_load_lds((const __attribute__((address_space(1))) void*)g,
                                   (__attribute__((address_space(3))) void*)l, 16, 0, 0);
}

// Stage [128][64] bf16 tile (256 threads, 4 units each) — used by score/pv.
__device__ __forceinline__ void stage_glds(const short* __restrict__ src, int ld,
                                           short* lds, int tid) {
  int w = tid >> 6;
#pragma unroll
  for (int it = 0; it < 4; ++it) {
    int u = it * 256 + tid;
    int r = u >> 3;
    int ssrc = (u ^ r) & 7;
    const short* g = src + (size_t)r * ld + ssrc * 8;
    short* lbase = lds + (size_t)(it * 256 + w * 64) * 8;
    gld16(g, lbase);
  }
}

// Stage a 256x32 region into packed [128][64] (512 threads, 2 units each).
__device__ __forceinline__ void stage_packed(const short* __restrict__ src, int ld,
                                             short* lds, int tid) {
  int w = tid >> 6;
#pragma unroll
  for (int it = 0; it < 2; ++it) {
    int u = it * 512 + tid;          // 16B-unit 0..1023
    int R = u >> 3, slotL = u & 7;
    int pre = slotL ^ (R & 7);       // pre-swizzled source slot (involution)
    int r = (R << 1) | (pre >> 2);
    int kc = pre & 3;
    const short* g = src + (size_t)r * ld + kc * 8;
    short* lbase = lds + (size_t)(it * 512 + w * 64) * 8;
    gld16(g, lbase);
  }
}

// 256-thread 128x128 K-step (score/pv): 8+8 ds_read_b128, 32 MFMA.
__device__ __forceinline__ void mfma_tile(const short* ldsA, const short* ldsB,
                                          f32x4 acc[4][4], int wm, int wn, int lr, int lk) {
#pragma unroll
  for (int c = 0; c < 2; ++c) {
    bf16x8 afr[4], bfr[4];
#pragma unroll
    for (int m = 0; m < 4; ++m)
      afr[m] = *(const bf16x8*)&ldsA[swz(wm * 64 + m * 16 + lr, c * 4 + lk)];
#pragma unroll
    for (int n = 0; n < 4; ++n)
      bfr[n] = *(const bf16x8*)&ldsB[swz(wn * 64 + n * 16 + lr, c * 4 + lk)];
#pragma unroll
    for (int m = 0; m < 4; ++m)
#pragma unroll
      for (int n = 0; n < 4; ++n)
        acc[m][n] = __builtin_amdgcn_mfma_f32_16x16x32_bf16(afr[m], bfr[n], acc[m][n], 0, 0, 0);
  }
}

// ---------------- W cast + transpose: Wt[n][k] = bf16(W[k][n]) ----------------
__global__ void wcast_kernel(const float* __restrict__ Wq, const float* __restrict__ Wk,
                             const float* __restrict__ Wv,
                             short* __restrict__ WtQ, short* __restrict__ WtK,
                             short* __restrict__ WtV) {
  int z = blockIdx.z;
  const float* W = (z == 0) ? Wq : (z == 1) ? Wk : Wv;
  short* Wt      = (z == 0) ? WtQ : (z == 1) ? WtK : WtV;
  __shared__ float tile[32][33];
  int r0 = blockIdx.y * 32, c0 = blockIdx.x * 32;
  int tx = threadIdx.x, ty = threadIdx.y;  // (32,8)
#pragma unroll
  for (int ii = 0; ii < 4; ++ii) {
    int r = ty * 4 + ii;
    tile[r][tx] = W[(size_t)(r0 + r) * Dd + c0 + tx];
  }
  __syncthreads();
#pragma unroll
  for (int ii = 0; ii < 4; ++ii) {
    int c = ty * 4 + ii;
    Wt[(size_t)(c0 + c) * Dd + r0 + tx] = f2bf(tile[tx][c]);
  }
}

// ---------------- fp32 -> bf16 cast (vectorized, memory-bound) ----------------
__global__ void cast_kernel(const float* __restrict__ src, short* __restrict__ dst) {
  size_t i = (size_t)blockIdx.x * blockDim.x + threadIdx.x;
  size_t stride = (size_t)gridDim.x * blockDim.x;
  const size_t N8 = (size_t)Bb * Ss * Dd / 8;
  for (; i < N8; i += stride) {
    float4 a = ((const float4*)src)[2 * i];
    float4 b = ((const float4*)src)[2 * i + 1];
    bf16x8 h;
    h[0] = f2bf(a.x); h[1] = f2bf(a.y); h[2] = f2bf(a.z); h[3] = f2bf(a.w);
    h[4] = f2bf(b.x); h[5] = f2bf(b.y); h[6] = f2bf(b.z); h[7] = f2bf(b.w);
    *(bf16x8*)(dst + i * 8) = h;
  }
}

// ---------------- 256x256 counted-vmcnt phase-pipelined projection GEMM -------
// out = A @ W^T + bias.  A bf16 [16384][1024], W bf16 [1024][1024] (row = out col).
// 512 thr = 8 waves (2M x 4N); per-wave 128x64; BK=32; tri-buffered LDS (96 KB);
// per K-tile 2 phases {ds_read / stage / barrier / setprio MFMA}; vmcnt(4) at
// tile end only (T3+T4). Tri-buffer => stage of t+2 never touches live bufs.
#define NT 32  // 1024 / 32
__launch_bounds__(512, 2)
__global__ void proj8_kernel(const short* __restrict__ A, const short* __restrict__ W,
                             const float* __restrict__ bias, short* __restrict__ out,
                             int tmode) {
  __shared__ short lds[3][2][128 * 64];   // [buf][0=A,1=B], 96 KB
  // XCD swizzle: 256 blocks; xcd = g&7; n fastest within XCD (A-panel L2 reuse).
  int g = blockIdx.x;
  int xcd = g & 7, j = g >> 3;
  int nblk = j & 3, mp = j >> 2;           // mp 0..7
  int mblk = mp * 8 + xcd;                 // 0..63
  int m0 = mblk * 256, n0 = nblk * 256;

  int tid = threadIdx.x;
  int lane = tid & 63, w = tid >> 6;
  int wm = w >> 2, wn = w & 3;             // 2 x 4 waves
  int lr = lane & 15, lk = lane >> 4;

  const short* Ab = A + (size_t)m0 * Dd;
  const short* Wb = W + (size_t)n0 * Dd;

  f32x4 acc[8][4] = {};

  // prologue: tiles 0,1 -> bufs 0,1
  stage_packed(Ab + 0, Dd, lds[0][0], tid);
  stage_packed(Wb + 0, Dd, lds[0][1], tid);
  stage_packed(Ab + 32, Dd, lds[1][0], tid);
  stage_packed(Wb + 32, Dd, lds[1][1], tid);
  asm volatile("s_waitcnt vmcnt(4)" ::: "memory");   // tile 0 landed
  __builtin_amdgcn_s_barrier();
  __builtin_amdgcn_sched_barrier(0);

  for (int t = 0; t < NT; ++t) {
    const short* la = lds[t % 3][0];
    const short* lb = lds[t % 3][1];
    bool pf = (t + 2) < NT;
    short* pa = lds[(t + 2) % 3][0];
    short* pb = lds[(t + 2) % 3][1];
    int kpre = (t + 2) * 32;

    bf16x8 bfr[4], afr[4];
    // ---- phase 0: B frags (kept for both phases) + A quadrant 0 ----
#pragma unroll
    for (int n = 0; n < 4; ++n)
      bfr[n] = *(const bf16x8*)&lb[swzp(wn * 64 + n * 16 + lr, lk)];
#pragma unroll
    for (int m = 0; m < 4; ++m)
      afr[m] = *(const bf16x8*)&la[swzp(wm * 128 + m * 16 + lr, lk)];
    if (pf) stage_packed(Ab + kpre, Dd, pa, tid);
    __builtin_amdgcn_s_barrier();
    __builtin_amdgcn_sched_barrier(0);
    __builtin_amdgcn_s_setprio(1);
#pragma unroll
    for (int m = 0; m < 4; ++m)
#pragma unroll
      for (int n = 0; n < 4; ++n)
        acc[m][n] = __builtin_amdgcn_mfma_f32_16x16x32_bf16(afr[m], bfr[n], acc[m][n], 0, 0, 0);
    __builtin_amdgcn_s_setprio(0);
    __builtin_amdgcn_s_barrier();
    __builtin_amdgcn_sched_barrier(0);
    // ---- phase 1: A quadrant 1 ----
#pragma unroll
    for (int m = 0; m < 4; ++m)
      afr[m] = *(const bf16x8*)&la[swzp(wm * 128 + 64 + m * 16 + lr, lk)];
    if (pf) stage_packed(Wb + kpre, Dd, pb, tid);
    __builtin_amdgcn_s_barrier();
    __builtin_amdgcn_sched_barrier(0);
    __builtin_amdgcn_s_setprio(1);
#pragma unroll
    for (int m = 0; m < 4; ++m)
#pragma unroll
      for (int n = 0; n < 4; ++n)
        acc[4 + m][n] = __builtin_amdgcn_mfma_f32_16x16x32_bf16(afr[m], bfr[n], acc[4 + m][n], 0, 0, 0);
    __builtin_amdgcn_s_setprio(0);
    // counted wait: ensure tile t+1 landed; keep t+2's 4 loads in flight.
    if (pf)                asm volatile("s_waitcnt vmcnt(4)" ::: "memory");
    else if (t + 1 < NT)   asm volatile("s_waitcnt vmcnt(0)" ::: "memory");
    __builtin_amdgcn_s_barrier();
    __builtin_amdgcn_sched_barrier(0);
  }

  // epilogue
#pragma unroll
  for (int m = 0; m < 8; ++m) {
    int mrow = wm * 128 + (m >> 2) * 64 + (m & 3) * 16 + lk * 4;
#pragma unroll
    for (int n = 0; n < 4; ++n) {
      int col = n0 + wn * 64 + n * 16 + lr;
      float bv_ = bias[col];
      if (tmode == 0) {
        int rbase = m0 + mrow;
#pragma unroll
        for (int rr = 0; rr < 4; ++rr)
          out[(size_t)(rbase + rr) * Dd + col] = f2bf(acc[m][n][rr] + bv_);
      } else {
        int grow = m0 + mrow;
        int bidx = grow / Ss;
        int s0 = grow & (Ss - 1);
        short4 h;
        h.x = f2bf(acc[m][n][0] + bv_);
        h.y = f2bf(acc[m][n][1] + bv_);
        h.z = f2bf(acc[m][n][2] + bv_);
        h.w = f2bf(acc[m][n][3] + bv_);
        *(short4*)&out[(size_t)bidx * Dd * Ss + (size_t)col * Ss + s0] = h;
      }
    }
  }
}

// ---------------- causal block-sparse scores: SP = bf16(mask(q@k^T/32)) ------
// Grid: 1088 1-D. XCD = batch; triangular (i,j) decode (no dead blocks).
__launch_bounds__(256, 4)
__global__ void score_kernel(const short* __restrict__ qb, const short* __restrict__ kb,
                             short* __restrict__ SP) {
  int d = blockIdx.x;
  int b = d & 7;
  int sidx = d >> 3;
  int i = (int)((sqrtf(8.f * sidx + 1.f) - 1.f) * 0.5f);
  while ((i + 1) * (i + 2) / 2 <= sidx) ++i;
  while (i * (i + 1) / 2 > sidx) --i;
  int j = sidx - i * (i + 1) / 2;    // j <= i

  __shared__ short ldsA[128 * 64];
  __shared__ short ldsB[128 * 64];
  int tid = threadIdx.x;
  int lane = tid & 63, w = tid >> 6;
  int wm = w >> 1, wn = w & 1;
  int lr = lane & 15, lk = lane >> 4;

  const short* Abase = qb + (size_t)b * Ss * Dd + (size_t)i * 128 * Dd;
  const short* Bbase = kb + (size_t)b * Ss * Dd + (size_t)j * 128 * Dd;

  f32x4 acc[4][4] = {};
  for (int k0 = 0; k0 < Dd; k0 += 64) {
    __syncthreads();
    stage_glds(Abase + k0, Dd, ldsA, tid);
    stage_glds(Bbase + k0, Dd, ldsB, tid);
    __syncthreads();
    mfma_tile(ldsA, ldsB, acc, wm, wn, lr, lk);
  }

  short* srow = SP + (size_t)b * Ss * Ss;
#pragma unroll
  for (int m = 0; m < 4; ++m)
#pragma unroll
    for (int n = 0; n < 4; ++n) {
      int colg = j * 128 + wn * 64 + n * 16 + lr;
      int rbase = i * 128 + wm * 64 + m * 16 + lk * 4;
#pragma unroll
      for (int rr = 0; rr < 4; ++rr) {
        int rowg = rbase + rr;
        float sv = acc[m][n][rr] * 0.03125f;  // 1/sqrt(1024)
        if (colg > rowg) sv = -1e9f;
        srow[(size_t)rowg * Ss + colg] = f2bf(sv);
      }
    }
}

// ---------------- row softmax, in place over SP (bf16) ----------------
__global__ void softmax_kernel(short* __restrict__ SP) {
  int row = blockIdx.x;
  int b = row >> 11;
  int q = row & (Ss - 1);
  int L = ((q >> 7) + 1) << 7;
  short* srow = SP + (size_t)b * Ss * Ss + (size_t)q * Ss;
  int tid = threadIdx.x;
  int lane = tid & 63, w = tid >> 6;

  float vals[8];
  int cnt = 0;
  float mx = -3.0e38f;
  for (int c = tid; c < L; c += 256) {
    float f = bf2f(srow[c]);
    vals[cnt++] = f;
    mx = fmaxf(mx, f);
  }
  __shared__ float red[8];
#pragma unroll
  for (int off = 32; off; off >>= 1) mx = fmaxf(mx, __shfl_xor(mx, off));
  if (lane == 0) red[w] = mx;
  __syncthreads();
  mx = fmaxf(fmaxf(red[0], red[1]), fmaxf(red[2], red[3]));

  float sum = 0.f;
  for (int k2 = 0; k2 < cnt; ++k2) {
    float e = __expf(vals[k2] - mx);
    vals[k2] = e;
    sum += e;
  }
#pragma unroll
  for (int off = 32; off; off >>= 1) sum += __shfl_xor(sum, off);
  if (lane == 0) red[4 + w] = sum;
  __syncthreads();
  sum = red[4] + red[5] + red[6] + red[7];
  float inv = 1.0f / sum;

  cnt = 0;
  for (int c = tid; c < L; c += 256) srow[c] = f2bf(vals[cnt++] * inv);
}

// ---------------- causal block-sparse PV: out = P @ v (fp32 out) ----------------
// Grid: 1024 1-D. XCD = batch; dblk fastest (P-tile L2 reuse within XCD).
__launch_bounds__(256, 4)
__global__ void pv_kernel(const short* __restrict__ SP, const short* __restrict__ vT,
                          float* __restrict__ out) {
  int d = blockIdx.x;
  int b = d & 7;
  int s = d >> 3;
  int i = s >> 3;
  int dblk = s & 7;

  __shared__ short ldsA[128 * 64];
  __shared__ short ldsB[128 * 64];
  int tid = threadIdx.x;
  int lane = tid & 63, w = tid >> 6;
  int wm = w >> 1, wn = w & 1;
  int lr = lane & 15, lk = lane >> 4;

  const short* Abase = SP + (size_t)b * Ss * Ss + (size_t)i * 128 * Ss;
  const short* Bbase = vT + (size_t)b * Dd * Ss + (size_t)dblk * 128 * Ss;
  int KL = (i + 1) * 128;

  f32x4 acc[4][4] = {};
  for (int k0 = 0; k0 < KL; k0 += 64) {
    __syncthreads();
    stage_glds(Abase + k0, Ss, ldsA, tid);
    stage_glds(Bbase + k0, Ss, ldsB, tid);
    __syncthreads();
    mfma_tile(ldsA, ldsB, acc, wm, wn, lr, lk);
  }

#pragma unroll
  for (int m = 0; m < 4; ++m)
#pragma unroll
    for (int n = 0; n < 4; ++n) {
      int colg = dblk * 128 + wn * 64 + n * 16 + lr;
      int rbase = i * 128 + wm * 64 + m * 16 + lk * 4;
#pragma unroll
      for (int rr = 0; rr < 4; ++rr)
        out[(size_t)b * Ss * Dd + (size_t)(rbase + rr) * Dd + colg] = acc[m][n][rr];
    }
}

extern "C" void kernel_launch(void* const* d_in, const int* in_sizes, int n_in,
                              void* d_out, int out_size, void* d_ws, size_t ws_size,
                              hipStream_t stream) {
  const float* Q  = (const float*)d_in[0];
  const float* K  = (const float*)d_in[1];
  const float* V  = (const float*)d_in[2];
  const float* Wq = (const float*)d_in[3];
  const float* Wk = (const float*)d_in[4];
  const float* Wv = (const float*)d_in[5];
  const float* bq = (const float*)d_in[6];
  const float* bk = (const float*)d_in[7];
  const float* bv = (const float*)d_in[8];
  float* out = (float*)d_out;

  char* ws = (char*)d_ws;
  size_t off = 0;
  short* WtQ = (short*)(ws + off); off += (size_t)Dd * Dd * 2;
  short* WtK = (short*)(ws + off); off += (size_t)Dd * Dd * 2;
  short* WtV = (short*)(ws + off); off += (size_t)Dd * Dd * 2;
  short* qb  = (short*)(ws + off); off += (size_t)Bb * Ss * Dd * 2;
  short* kb  = (short*)(ws + off); off += (size_t)Bb * Ss * Dd * 2;
  short* vT  = (short*)(ws + off); off += (size_t)Bb * Ss * Dd * 2;
  short* SP  = (short*)(ws + off); off += (size_t)Bb * Ss * Ss * 2;  // scores/P in place
  short* Xbf = SP;  // bf16 input cast buffer ALIASES SP (dead until score_kernel)
  (void)ws_size; (void)in_sizes; (void)n_in; (void)out_size;

  wcast_kernel<<<dim3(32, 32, 3), dim3(32, 8), 0, stream>>>(Wq, Wk, Wv, WtQ, WtK, WtV);

  cast_kernel<<<1024, 256, 0, stream>>>(Q, Xbf);
  proj8_kernel<<<256, 512, 0, stream>>>(Xbf, WtQ, bq, qb, 0);
  cast_kernel<<<1024, 256, 0, stream>>>(K, Xbf);
  proj8_kernel<<<256, 512, 0, stream>>>(Xbf, WtK, bk, kb, 0);
  cast_kernel<<<1024, 256, 0, stream>>>(V, Xbf);
  proj8_kernel<<<256, 512, 0, stream>>>(Xbf, WtV, bv, vT, 1);

  score_kernel<<<dim3(1088), 256, 0, stream>>>(qb, kb, SP);
  softmax_kernel<<<dim3(Bb * Ss), 256, 0, stream>>>(SP);
  pv_kernel<<<dim3(1024), 256, 0, stream>>>(SP, vT, out);
}